// Round 7
// baseline (137.711 us; speedup 1.0000x reference)
//
#include <hip/hip_runtime.h>
#include <hip/hip_bf16.h>

#define NB 32
#define NS 4
#define NL 64
#define NC 32
#define NH 4
#define ND 8
#define NCP 16

using fp = const float* __restrict__;

// ---------------------------------------------------------------------------
// K1 v8: 256 blocks (b,s,half) x 1024 threads = 16 waves, 4 waves/SIMD.
// Same total work as v6 (no duplication except embed+LN), per-thread chains
// halved: QKV 2 e-ch/wave, attn 8 lanes/(row,head) 8 m's/lane, out-proj
// 1 ch/thread. Weight staging parallelized 4-way. LDS identical to v6.
// ---------------------------------------------------------------------------
__global__ __launch_bounds__(1024) void k1_attn(
    fp ctcf, fp hac, fp me1, fp me3, fp bulk,
    fp we_w, fp we_b, fp pos, fp mn_g, fp mn_b,
    fp wq, fp bq, fp wk, fp bk, fp wv, fp bv,
    fp wo, fp bo, fp an_g, fp an_b,
    fp conv_w, fp conv_b, fp gate_w, fp gate_b,
    float* __restrict__ xpostT)
{
    __shared__ __align__(16) float q2[NL*36];
    __shared__ __align__(16) float k2[NL*36];
    __shared__ __align__(16) float v2[NL*36];
    __shared__ __align__(16) float x2[NL*36];
    __shared__ __align__(16) float a2[NL*36];
    __shared__ float bs[32*65];              // bulk rows, 65-stride
    __shared__ __align__(16) float ws_wq[NC*NC];
    __shared__ __align__(16) float ws_wk[NC*NC];
    __shared__ __align__(16) float ws_wv[NC*NC];
    __shared__ __align__(16) float ws_wo[NC*NC];   // f4-slot swizzled
    __shared__ __align__(16) float ws_gw[NH*ND*ND];
    __shared__ __align__(16) float ws_par[352];
    // ws_par: we_w 0, we_b 32, mn_g 64, mn_b 96, bq 128, bk 160, bv 192,
    //         bo 224, an_g 256, an_b 288, gate_b 320

    const int t    = threadIdx.x;
    const int w2   = t >> 6;           // wave 0..15
    const int l    = t & 63;
    const int bx   = blockIdx.x;
    const int b    = bx >> 3;
    const int s    = (bx >> 1) & 3;
    const int half = bx & 1;

    // ---- stage weights/params (4-way parallel) + bulk ----
    if      (t < 256) ((float4*)ws_wq)[t]       = ((const float4*)wq)[t];
    else if (t < 512) ((float4*)ws_wk)[t - 256] = ((const float4*)wk)[t - 256];
    else if (t < 768) ((float4*)ws_wv)[t - 512] = ((const float4*)wv)[t - 512];
    else {
        int u = t - 768;                       // wo, swizzled f4 slots
        int c = u >> 3, k4 = u & 7;
        ((float4*)ws_wo)[c*8 + (k4 ^ ((c >> 1) & 7))] = ((const float4*)wo)[u];
    }
    if (t < 64) ((float4*)ws_gw)[t] = ((const float4*)gate_w)[t];
    else if (t < 152){
        int p = t - 64;
        const float* sp = (p < 8)  ? we_w : (p < 16) ? we_b
                        : (p < 24) ? mn_g : (p < 32) ? mn_b
                        : (p < 40) ? bq   : (p < 48) ? bk
                        : (p < 56) ? bv   : (p < 64) ? bo
                        : (p < 72) ? an_g : (p < 80) ? an_b : gate_b;
        ((float4*)ws_par)[p] = ((const float4*)sp)[p & 7];
    }
    if (t >= 512){                             // bulk: 512 f4 on waves 8-15
        int idx = t - 512;
        float4 v = ((const float4*)(bulk + b*NL*NL + half*32*NL))[idx];
        int row = idx >> 4, col = (idx & 15) << 2;
        float* dst = &bs[row*65 + col];
        dst[0] = v.x; dst[1] = v.y; dst[2] = v.z; dst[3] = v.w;
    }

    fp sigp = (s == 0) ? ctcf : (s == 1) ? hac : (s == 2) ? me1 : me3;
    const float sig = sigp[b*NL + l];
    __syncthreads();                            // barrier 1: staging done

    const float4* pws = (const float4*)ws_par;

    // ---- phase 1: embed + LN (LDS broadcasts), every thread for its l ----
    float x[NC];
    float mean = 0.f;
#pragma unroll
    for (int k4 = 0; k4 < 8; k4++){
        float4 ww = pws[k4];
        float4 wb = pws[8 + k4];
        float4 pp = ((const float4*)pos)[l*8 + k4];
        x[4*k4+0] = sig*ww.x + wb.x + pp.x;
        x[4*k4+1] = sig*ww.y + wb.y + pp.y;
        x[4*k4+2] = sig*ww.z + wb.z + pp.z;
        x[4*k4+3] = sig*ww.w + wb.w + pp.w;
        mean += x[4*k4+0] + x[4*k4+1] + x[4*k4+2] + x[4*k4+3];
    }
    mean *= (1.f/NC);
    float var = 0.f;
#pragma unroll
    for (int c = 0; c < NC; c++){ float d = x[c] - mean; var += d*d; }
    var *= (1.f/NC);
    float inv = rsqrtf(var + 1e-5f);
#pragma unroll
    for (int k4 = 0; k4 < 8; k4++){
        float4 gg = pws[16 + k4];
        float4 bb = pws[24 + k4];
        x[4*k4+0] = (x[4*k4+0] - mean)*inv*gg.x + bb.x;
        x[4*k4+1] = (x[4*k4+1] - mean)*inv*gg.y + bb.y;
        x[4*k4+2] = (x[4*k4+2] - mean)*inv*gg.z + bb.z;
        x[4*k4+3] = (x[4*k4+3] - mean)*inv*gg.w + bb.w;
    }

    // ---- QKV 2-wide slice per wave (e = 2*w2, 2*w2+1) ----
    {
        float aqv[2], akv[2], avv[2];
#pragma unroll
        for (int e2 = 0; e2 < 2; e2++){
            const int e = (w2 << 1) + e2;
            float aq = ws_par[128 + e], ak = ws_par[160 + e], av = ws_par[192 + e];
#pragma unroll
            for (int k4 = 0; k4 < 8; k4++){
                float4 wq4 = *(const float4*)&ws_wq[e*NC + 4*k4];
                float4 wk4 = *(const float4*)&ws_wk[e*NC + 4*k4];
                float4 wv4 = *(const float4*)&ws_wv[e*NC + 4*k4];
                float x0 = x[4*k4+0], x1 = x[4*k4+1], x2v = x[4*k4+2], x3 = x[4*k4+3];
                aq += wq4.x*x0 + wq4.y*x1 + wq4.z*x2v + wq4.w*x3;
                ak += wk4.x*x0 + wk4.y*x1 + wk4.z*x2v + wk4.w*x3;
                av += wv4.x*x0 + wv4.y*x1 + wv4.z*x2v + wv4.w*x3;
            }
            aqv[e2] = aq; akv[e2] = ak; avv[e2] = av;
        }
        const int h    = w2 >> 2;                 // head owning e-pair
        const int slth = h ^ (l >> 4);
        const int off  = l*36 + (slth << 3) + ((w2 & 3) << 1);
        *(float2*)&q2[off] = make_float2(aqv[0], aqv[1]);
        *(float2*)&k2[off] = make_float2(akv[0], akv[1]);
        *(float2*)&v2[off] = make_float2(avv[0], avv[1]);
        // x slice: waves 0..7 write quad w2 (quad-swizzled)
        if (w2 < 8){
            float xa = 0.f, xb2 = 0.f, xc = 0.f, xd = 0.f;
#pragma unroll
            for (int ww = 0; ww < 8; ww++)
                if (ww == w2){ xa = x[4*ww]; xb2 = x[4*ww+1]; xc = x[4*ww+2]; xd = x[4*ww+3]; }
            *(float4*)&x2[l*36 + ((w2 ^ (l >> 4)) << 2)] = make_float4(xa, xb2, xc, xd);
        }
    }
    __syncthreads();                            // barrier 2

    // ---- phase 2: attention; 4 waves/head, 8 lanes per (row,head) ----
    {
        const int h   = w2 >> 2;
        const int sub = ((w2 & 3) << 6) | l;   // 0..255
        const int rl  = sub >> 3;              // local row 0..31
        const int q8  = sub & 7;               // m-eighth
        const int r   = half*32 + rl;
        const int m0  = q8 << 3;

        const int qoff = r*36 + ((h ^ (r >> 4)) << 3);
        float4 qa = *(const float4*)&q2[qoff];
        float4 qb = *(const float4*)&q2[qoff + 4];

        const float rs8 = 0.35355339059327373f;
        const float cw = conv_w[h], cb = conv_b[h];
        const float* bsr = &bs[rl*65];
        float srow[8];
        float mx = -1e30f;
#pragma unroll
        for (int mi = 0; mi < 8; mi++){
            int m  = m0 + mi;
            int kb = m*36 + ((h ^ (m >> 4)) << 3);
            float4 ka  = *(const float4*)&k2[kb];
            float4 kb4 = *(const float4*)&k2[kb + 4];
            float dot = qa.x*ka.x + qa.y*ka.y + qa.z*ka.z + qa.w*ka.w
                      + qb.x*kb4.x + qb.y*kb4.y + qb.z*kb4.z + qb.w*kb4.w;
            float vv = dot*rs8 + bsr[m]*cw + cb;
            srow[mi] = vv;
            mx = fmaxf(mx, vv);
        }
        mx = fmaxf(mx, __shfl_xor(mx, 1));
        mx = fmaxf(mx, __shfl_xor(mx, 2));
        mx = fmaxf(mx, __shfl_xor(mx, 4));
        float sm = 0.f;
#pragma unroll
        for (int mi = 0; mi < 8; mi++){ srow[mi] = __expf(srow[mi] - mx); sm += srow[mi]; }
        sm += __shfl_xor(sm, 1);
        sm += __shfl_xor(sm, 2);
        sm += __shfl_xor(sm, 4);
        float is = 1.f / sm;

        float4 oa = make_float4(0.f,0.f,0.f,0.f);
        float4 ob = make_float4(0.f,0.f,0.f,0.f);
#pragma unroll
        for (int mi = 0; mi < 8; mi++){
            int m  = m0 + mi;
            int vb = m*36 + ((h ^ (m >> 4)) << 3);
            float a = srow[mi] * is;
            float4 va  = *(const float4*)&v2[vb];
            float4 vb4 = *(const float4*)&v2[vb + 4];
            oa.x += a*va.x;  oa.y += a*va.y;  oa.z += a*va.z;  oa.w += a*va.w;
            ob.x += a*vb4.x; ob.y += a*vb4.y; ob.z += a*vb4.z; ob.w += a*vb4.w;
        }
#define RED3(f) f += __shfl_xor(f, 1); f += __shfl_xor(f, 2); f += __shfl_xor(f, 4);
        RED3(oa.x) RED3(oa.y) RED3(oa.z) RED3(oa.w)
        RED3(ob.x) RED3(ob.y) RED3(ob.z) RED3(ob.w)
#undef RED3

        // gate: lane owns channel q8
        const float* gwl = &ws_gw[(h*ND + q8)*ND];
        float4 g1 = *(const float4*)gwl;
        float4 g2 = *(const float4*)(gwl + 4);
        float g = ws_par[320 + h*ND + q8]
                + g1.x*oa.x + g1.y*oa.y + g1.z*oa.z + g1.w*oa.w
                + g2.x*ob.x + g2.y*ob.y + g2.z*ob.z + g2.w*ob.w;
        float oc = oa.x;
        if (q8 == 1) oc = oa.y;
        if (q8 == 2) oc = oa.z;
        if (q8 == 3) oc = oa.w;
        if (q8 == 4) oc = ob.x;
        if (q8 == 5) oc = ob.y;
        if (q8 == 6) oc = ob.z;
        if (q8 == 7) oc = ob.w;
        a2[r*36 + h*8 + q8] = oc * (1.f/(1.f + __expf(-g)));
    }
    __syncthreads();                            // barrier 3

    // ---- phase 3: out-proj (1 ch/thread) + residual + shfl-LN + store ----
    {
        const int r3 = t >> 5;             // local row 0..31
        const int c  = t & 31;             // channel
        const int rg = half*32 + r3;       // global row
        float acc = ws_par[224 + c];
#pragma unroll
        for (int k4 = 0; k4 < 8; k4++){
            float4 av = *(const float4*)&a2[rg*36 + (k4 << 2)];
            float4 w1 = ((const float4*)ws_wo)[c*8 + (k4 ^ ((c >> 1) & 7))];
            acc += av.x*w1.x + av.y*w1.y + av.z*w1.z + av.w*w1.w;
        }
        float xr = x2[rg*36 + (((c >> 2) ^ (rg >> 4)) << 2) + (c & 3)];
        float val = xr + acc;
        float ps = val, pq = val*val;
        ps += __shfl_xor(ps, 1);  pq += __shfl_xor(pq, 1);
        ps += __shfl_xor(ps, 2);  pq += __shfl_xor(pq, 2);
        ps += __shfl_xor(ps, 4);  pq += __shfl_xor(pq, 4);
        ps += __shfl_xor(ps, 8);  pq += __shfl_xor(pq, 8);
        ps += __shfl_xor(ps, 16); pq += __shfl_xor(pq, 16);
        float mn = ps * (1.f/NC);
        float vr = pq * (1.f/NC) - mn*mn;
        float iv = rsqrtf(vr + 1e-5f);
        xpostT[((b*NS + s)*NL + rg)*NC + c] =
            (val - mn)*iv*ws_par[256 + c] + ws_par[288 + c];
    }
}

// ---------------------------------------------------------------------------
// K23 v4 (byte-identical to R6 best): f4-granular u-passes, async-staged
// pp_w, norm folded out, 4 barriers, static f[] indexing.
// ---------------------------------------------------------------------------
__global__ __launch_bounds__(256) void k23_pair(
    const float* __restrict__ xpostT, fp pp_w,
    fp pp_b, fp ada_g, fp ada_b, fp ada_alpha,
    float* __restrict__ out)
{
    __shared__ float ppws[8*NC*NC];   // 8192 floats, 32 KB (per pass)
    __shared__ float mh[NC*66];       // raw max over tracks, [c][66]
    __shared__ float u[NCP*4*NC];     // 2048 floats
    __shared__ float nrm_s[NL];       // |m_i| per row

    const int b  = blockIdx.x >> 4;
    const int it = blockIdx.x & 15;
    const int t  = threadIdx.x;
    const int w  = t >> 6;
    const int j  = t & 63;

    float4 s1[8];
#pragma unroll
    for (int k = 0; k < 8; k++) s1[k] = ((const float4*)pp_w)[k*256 + t];

    const float4* xb4 = (const float4*)(xpostT + b*NS*NL*NC);
#pragma unroll
    for (int k = 0; k < 2; k++){
        int idx = k*256 + t;
        float4 v0 = xb4[idx];
        float4 v1 = xb4[512  + idx];
        float4 v2 = xb4[1024 + idx];
        float4 v3 = xb4[1536 + idx];
        float m0 = fmaxf(fmaxf(v0.x, v1.x), fmaxf(v2.x, v3.x));
        float m1 = fmaxf(fmaxf(v0.y, v1.y), fmaxf(v2.y, v3.y));
        float m2 = fmaxf(fmaxf(v0.z, v1.z), fmaxf(v2.z, v3.z));
        float m3 = fmaxf(fmaxf(v0.w, v1.w), fmaxf(v2.w, v3.w));
        int l = idx >> 3, c4 = idx & 7;
        mh[(4*c4+0)*66 + l] = m0;
        mh[(4*c4+1)*66 + l] = m1;
        mh[(4*c4+2)*66 + l] = m2;
        mh[(4*c4+3)*66 + l] = m3;
    }
#pragma unroll
    for (int k = 0; k < 8; k++) ((float4*)ppws)[k*256 + t] = s1[k];
    __syncthreads();

    if (t < NL){
        float sq = 0.f;
#pragma unroll
        for (int c = 0; c < NC; c++){ float v = mh[c*66 + t]; sq += v*v; }
        nrm_s[t] = sqrtf(sq);
    }

    float4 s2[8];
#pragma unroll
    for (int k = 0; k < 8; k++) s2[k] = ((const float4*)pp_w)[2048 + k*256 + t];

    const int dq  = t & 7;            // d-quad
    const int ipz = (t >> 3) & 3;     // i within tile
    const int plz = t >> 5;           // p-slice 0..7
    const int iz  = it*4 + ipz;
    {
        float4 acc = make_float4(0.f, 0.f, 0.f, 0.f);
        const float*  mrow = &mh[iz];
        const float4* wrow = (const float4*)&ppws[plz*1024 + (dq << 2)];
#pragma unroll
        for (int c = 0; c < NC; c++){
            float  mhv = mrow[c*66];
            float4 wv  = wrow[c*8];
            acc.x += mhv*wv.x; acc.y += mhv*wv.y;
            acc.z += mhv*wv.z; acc.w += mhv*wv.w;
        }
        *(float4*)&u[plz*128 + ipz*32 + (dq << 2)] = acc;
    }
    __syncthreads();
#pragma unroll
    for (int k = 0; k < 8; k++) ((float4*)ppws)[k*256 + t] = s2[k];
    __syncthreads();

    {
        float4 acc = make_float4(0.f, 0.f, 0.f, 0.f);
        const float*  mrow = &mh[iz];
        const float4* wrow = (const float4*)&ppws[plz*1024 + (dq << 2)];
#pragma unroll
        for (int c = 0; c < NC; c++){
            float  mhv = mrow[c*66];
            float4 wv  = wrow[c*8];
            acc.x += mhv*wv.x; acc.y += mhv*wv.y;
            acc.z += mhv*wv.z; acc.w += mhv*wv.w;
        }
        *(float4*)&u[(8 + plz)*128 + ipz*32 + (dq << 2)] = acc;
    }
    __syncthreads();

    float md[NC];
#pragma unroll
    for (int c = 0; c < NC; c++) md[c] = mh[c*66 + j];

    const int i = it*4 + w;
    float f[NCP];
#pragma unroll
    for (int p = 0; p < NCP; p++){
        float a = 0.f;
#pragma unroll
        for (int k4 = 0; k4 < 8; k4++){
            float4 uv = *(const float4*)&u[p*128 + w*32 + (k4 << 2)];
            a += uv.x*md[4*k4+0] + uv.y*md[4*k4+1] + uv.z*md[4*k4+2] + uv.w*md[4*k4+3];
        }
        f[p] = a;
    }

    const float sc = 1.f / fmaxf(nrm_s[i] * nrm_s[j], 1e-6f);
    const float alpha = ada_alpha[0];
    float fsum = 0.f, fsq = 0.f;
#pragma unroll
    for (int p = 0; p < NCP; p++){
        float v = f[p]*sc + pp_b[p];
        f[p] = v; fsum += v; fsq += v*v;
    }
    float fmean = fsum * (1.f/NCP);
    float fvar  = fsq * (1.f/NCP) - fmean*fmean;
    float finv  = rsqrtf(fvar + 1e-5f);
#pragma unroll
    for (int p = 0; p < NCP; p++){
        float v = f[p] + alpha * ((f[p] - fmean)*finv*ada_g[p] + ada_b[p]);
        out[((b*NCP + p)*NL + i)*NL + j] = v / (1.f + __expf(-v));
    }
}

extern "C" void kernel_launch(void* const* d_in, const int* in_sizes, int n_in,
                              void* d_out, int out_size, void* d_ws, size_t ws_size,
                              hipStream_t stream)
{
    float* xpostT = (float*)d_ws;                    // 32*4*64*32 = 262144 f32

    k1_attn<<<NB*NS*2, 1024, 0, stream>>>(
        (fp)d_in[0], (fp)d_in[1], (fp)d_in[2], (fp)d_in[3], (fp)d_in[4],
        (fp)d_in[5], (fp)d_in[6], (fp)d_in[7], (fp)d_in[8], (fp)d_in[9],
        (fp)d_in[10], (fp)d_in[11], (fp)d_in[12], (fp)d_in[13], (fp)d_in[14], (fp)d_in[15],
        (fp)d_in[16], (fp)d_in[17], (fp)d_in[18], (fp)d_in[19],
        (fp)d_in[20], (fp)d_in[21], (fp)d_in[22], (fp)d_in[23], xpostT);

    k23_pair<<<NB*16, 256, 0, stream>>>(
        xpostT, (fp)d_in[24], (fp)d_in[25], (fp)d_in[26], (fp)d_in[27], (fp)d_in[28],
        (float*)d_out);
}

// Round 8
// 137.062 us; speedup vs baseline: 1.0047x; 1.0047x over previous
//
#include <hip/hip_runtime.h>
#include <hip/hip_bf16.h>

#define NB 32
#define NS 4
#define NL 64
#define NC 32
#define NH 4
#define ND 8
#define NCP 16

using fp = const float* __restrict__;

// ---------------------------------------------------------------------------
// K1 v9 = R6's v6 (the 136.5 µs best) + pos preloaded into registers BEFORE
// barrier 1 (T14: the barrier drains vmcnt anyway, so the pos latency rides
// the staging wait instead of heading phase 1's chain). Math identical.
// ---------------------------------------------------------------------------
__global__ __launch_bounds__(512) void k1_attn(
    fp ctcf, fp hac, fp me1, fp me3, fp bulk,
    fp we_w, fp we_b, fp pos, fp mn_g, fp mn_b,
    fp wq, fp bq, fp wk, fp bk, fp wv, fp bv,
    fp wo, fp bo, fp an_g, fp an_b,
    fp conv_w, fp conv_b, fp gate_w, fp gate_b,
    float* __restrict__ xpostT)
{
    __shared__ __align__(16) float q2[NL*36];
    __shared__ __align__(16) float k2[NL*36];
    __shared__ __align__(16) float v2[NL*36];
    __shared__ __align__(16) float x2[NL*36];
    __shared__ __align__(16) float a2[NL*36];
    __shared__ float bs[32*65];              // bulk rows, 65-stride (2-way reads)
    __shared__ __align__(16) float ws_wq[NC*NC];
    __shared__ __align__(16) float ws_wk[NC*NC];
    __shared__ __align__(16) float ws_wv[NC*NC];
    __shared__ __align__(16) float ws_wo[NC*NC];   // f4-slot swizzled
    __shared__ __align__(16) float ws_gw[NH*ND*ND];
    __shared__ __align__(16) float ws_par[352];
    // ws_par: we_w 0, we_b 32, mn_g 64, mn_b 96, bq 128, bk 160, bv 192,
    //         bo 224, an_g 256, an_b 288, gate_b 320

    const int t    = threadIdx.x;
    const int w    = t >> 6;           // wave 0..7
    const int l    = t & 63;
    const int bx   = blockIdx.x;
    const int b    = bx >> 3;
    const int s    = (bx >> 1) & 3;
    const int half = bx & 1;

    // pos preload: issue the 8 f4 loads NOW so their latency overlaps the
    // staging + barrier wait (the barrier drains vmcnt regardless).
    float4 pp_r[8];
#pragma unroll
    for (int k4 = 0; k4 < 8; k4++) pp_r[k4] = ((const float4*)pos)[l*8 + k4];

    fp sigp = (s == 0) ? ctcf : (s == 1) ? hac : (s == 2) ? me1 : me3;
    const float sig = sigp[b*NL + l];

    // ---- stage weights/params (coalesced f4) + bulk (65-stride) ----
    if (t < 256) ((float4*)ws_wq)[t]       = ((const float4*)wq)[t];
    else         ((float4*)ws_wk)[t - 256] = ((const float4*)wk)[t - 256];

    if (t < 256) ((float4*)ws_wv)[t] = ((const float4*)wv)[t];
    else {
        int u = t - 256;
        if (u < 64) ((float4*)ws_gw)[u] = ((const float4*)gate_w)[u];
        else if (u < 152){
            int p = u - 64;
            const float* sp = (p < 8)  ? we_w : (p < 16) ? we_b
                            : (p < 24) ? mn_g : (p < 32) ? mn_b
                            : (p < 40) ? bq   : (p < 48) ? bk
                            : (p < 56) ? bv   : (p < 64) ? bo
                            : (p < 72) ? an_g : (p < 80) ? an_b : gate_b;
            ((float4*)ws_par)[p] = ((const float4*)sp)[p & 7];
        }
    }
    if (t < 256){                               // wo, swizzled f4 slots
        int c = t >> 3, k4 = t & 7;
        ((float4*)ws_wo)[c*8 + (k4 ^ ((c >> 1) & 7))] = ((const float4*)wo)[t];
    }
    {
        float4 v = ((const float4*)(bulk + b*NL*NL + half*32*NL))[t];
        int row = t >> 4, col = (t & 15) << 2;
        float* dst = &bs[row*65 + col];
        dst[0] = v.x; dst[1] = v.y; dst[2] = v.z; dst[3] = v.w;
    }
    __syncthreads();                            // barrier 1: staging done

    const float4* pws = (const float4*)ws_par;

    // ---- phase 1: embed + LN (LDS broadcasts, pos already in regs) ----
    float x[NC];
    float mean = 0.f;
#pragma unroll
    for (int k4 = 0; k4 < 8; k4++){
        float4 ww = pws[k4];
        float4 wb = pws[8 + k4];
        float4 pp = pp_r[k4];
        x[4*k4+0] = sig*ww.x + wb.x + pp.x;
        x[4*k4+1] = sig*ww.y + wb.y + pp.y;
        x[4*k4+2] = sig*ww.z + wb.z + pp.z;
        x[4*k4+3] = sig*ww.w + wb.w + pp.w;
        mean += x[4*k4+0] + x[4*k4+1] + x[4*k4+2] + x[4*k4+3];
    }
    mean *= (1.f/NC);
    float var = 0.f;
#pragma unroll
    for (int c = 0; c < NC; c++){ float d = x[c] - mean; var += d*d; }
    var *= (1.f/NC);
    float inv = rsqrtf(var + 1e-5f);
#pragma unroll
    for (int k4 = 0; k4 < 8; k4++){
        float4 gg = pws[16 + k4];
        float4 bb = pws[24 + k4];
        x[4*k4+0] = (x[4*k4+0] - mean)*inv*gg.x + bb.x;
        x[4*k4+1] = (x[4*k4+1] - mean)*inv*gg.y + bb.y;
        x[4*k4+2] = (x[4*k4+2] - mean)*inv*gg.z + bb.z;
        x[4*k4+3] = (x[4*k4+3] - mean)*inv*gg.w + bb.w;
    }

    // ---- QKV 4-wide slice from LDS weights ----
    {
        float aqv[4], akv[4], avv[4];
#pragma unroll
        for (int e4 = 0; e4 < 4; e4++){
            const int e = (w << 2) + e4;
            float aq = ws_par[128 + e], ak = ws_par[160 + e], av = ws_par[192 + e];
#pragma unroll
            for (int k4 = 0; k4 < 8; k4++){
                float4 wq4 = *(const float4*)&ws_wq[e*NC + 4*k4];
                float4 wk4 = *(const float4*)&ws_wk[e*NC + 4*k4];
                float4 wv4 = *(const float4*)&ws_wv[e*NC + 4*k4];
                float x0 = x[4*k4+0], x1 = x[4*k4+1], x2v = x[4*k4+2], x3 = x[4*k4+3];
                aq += wq4.x*x0 + wq4.y*x1 + wq4.z*x2v + wq4.w*x3;
                ak += wk4.x*x0 + wk4.y*x1 + wk4.z*x2v + wk4.w*x3;
                av += wv4.x*x0 + wv4.y*x1 + wv4.z*x2v + wv4.w*x3;
            }
            aqv[e4] = aq; akv[e4] = ak; avv[e4] = av;
        }
        const int slt = ((w >> 1) ^ (l >> 4));
        const int kh  = (w & 1);
        const int off = l*36 + slt*8 + kh*4;
        *(float4*)&q2[off] = make_float4(aqv[0], aqv[1], aqv[2], aqv[3]);
        *(float4*)&k2[off] = make_float4(akv[0], akv[1], akv[2], akv[3]);
        *(float4*)&v2[off] = make_float4(avv[0], avv[1], avv[2], avv[3]);
        float xa = 0.f, xb2 = 0.f, xc = 0.f, xd = 0.f;
#pragma unroll
        for (int ww = 0; ww < 8; ww++)
            if (ww == w){ xa = x[4*ww]; xb2 = x[4*ww+1]; xc = x[4*ww+2]; xd = x[4*ww+3]; }
        *(float4*)&x2[l*36 + ((w ^ (l >> 4)) << 2)] = make_float4(xa, xb2, xc, xd);
    }
    __syncthreads();                            // barrier 2

    // ---- phase 2: attention; head h = w>>1, 4 lanes per row, b128 frags ----
    {
        const int h   = w >> 1;
        const int sub = ((w & 1) << 6) | l;
        const int rl  = sub >> 2;
        const int q4  = sub & 3;
        const int r   = half*32 + rl;
        const int m0  = q4 << 4;

        const int qoff = r*36 + ((h ^ (r >> 4)) << 3);
        float4 qa = *(const float4*)&q2[qoff];
        float4 qb = *(const float4*)&q2[qoff + 4];

        const float rs8 = 0.35355339059327373f;
        const float cw = conv_w[h], cb = conv_b[h];
        const float* bsr = &bs[rl*65];
        float srow[16];
        float mx = -1e30f;
#pragma unroll
        for (int mi = 0; mi < 16; mi++){
            int m  = m0 + mi;
            int kb = m*36 + ((h ^ (m >> 4)) << 3);
            float4 ka  = *(const float4*)&k2[kb];
            float4 kb4 = *(const float4*)&k2[kb + 4];
            float dot = qa.x*ka.x + qa.y*ka.y + qa.z*ka.z + qa.w*ka.w
                      + qb.x*kb4.x + qb.y*kb4.y + qb.z*kb4.z + qb.w*kb4.w;
            float vv = dot*rs8 + bsr[m]*cw + cb;
            srow[mi] = vv;
            mx = fmaxf(mx, vv);
        }
        mx = fmaxf(mx, __shfl_xor(mx, 1));
        mx = fmaxf(mx, __shfl_xor(mx, 2));
        float sm = 0.f;
#pragma unroll
        for (int mi = 0; mi < 16; mi++){ srow[mi] = __expf(srow[mi] - mx); sm += srow[mi]; }
        sm += __shfl_xor(sm, 1);
        sm += __shfl_xor(sm, 2);
        float is = 1.f / sm;

        float4 oa = make_float4(0.f,0.f,0.f,0.f);
        float4 ob = make_float4(0.f,0.f,0.f,0.f);
#pragma unroll
        for (int mi = 0; mi < 16; mi++){
            int m  = m0 + mi;
            int vb = m*36 + ((h ^ (m >> 4)) << 3);
            float a = srow[mi] * is;
            float4 va  = *(const float4*)&v2[vb];
            float4 vb4 = *(const float4*)&v2[vb + 4];
            oa.x += a*va.x;  oa.y += a*va.y;  oa.z += a*va.z;  oa.w += a*va.w;
            ob.x += a*vb4.x; ob.y += a*vb4.y; ob.z += a*vb4.z; ob.w += a*vb4.w;
        }
#define RED2(f) f += __shfl_xor(f, 1); f += __shfl_xor(f, 2);
        RED2(oa.x) RED2(oa.y) RED2(oa.z) RED2(oa.w)
        RED2(ob.x) RED2(ob.y) RED2(ob.z) RED2(ob.w)
#undef RED2

        const int c8l = q4 << 1;
        const float* gwl = &ws_gw[(h*ND + c8l)*ND];
        float4 g1 = *(const float4*)gwl;
        float4 g2 = *(const float4*)(gwl + 4);
        float4 g3 = *(const float4*)(gwl + 8);
        float4 g4 = *(const float4*)(gwl + 12);
        float gl = ws_par[320 + h*ND + c8l]
                 + g1.x*oa.x + g1.y*oa.y + g1.z*oa.z + g1.w*oa.w
                 + g2.x*ob.x + g2.y*ob.y + g2.z*ob.z + g2.w*ob.w;
        float gh = ws_par[320 + h*ND + c8l + 1]
                 + g3.x*oa.x + g3.y*oa.y + g3.z*oa.z + g3.w*oa.w
                 + g4.x*ob.x + g4.y*ob.y + g4.z*ob.z + g4.w*ob.w;
        float olo, ohi;
        if      (q4 == 0){ olo = oa.x; ohi = oa.y; }
        else if (q4 == 1){ olo = oa.z; ohi = oa.w; }
        else if (q4 == 2){ olo = ob.x; ohi = ob.y; }
        else             { olo = ob.z; ohi = ob.w; }
        float vlo = olo * (1.f/(1.f + __expf(-gl)));
        float vhi = ohi * (1.f/(1.f + __expf(-gh)));
        *(float2*)&a2[r*36 + h*8 + c8l] = make_float2(vlo, vhi);
    }
    __syncthreads();                            // barrier 3

    // ---- phase 3: out-proj (2 ch/thread) + residual + shfl-LN + store ----
    {
        const int rg = t >> 4;
        const int cg = t & 15;
        const int r3 = half*32 + rg;
        const int c0 = cg << 1;
        float accL = ws_par[224 + c0], accH = ws_par[224 + c0 + 1];
#pragma unroll
        for (int k4 = 0; k4 < 8; k4++){
            float4 av = *(const float4*)&a2[r3*36 + (k4 << 2)];
            float4 w1 = ((const float4*)ws_wo)[c0*8 + (k4 ^ (cg & 7))];
            float4 w2 = ((const float4*)ws_wo)[(c0 + 1)*8 + (k4 ^ (cg & 7))];
            accL += av.x*w1.x + av.y*w1.y + av.z*w1.z + av.w*w1.w;
            accH += av.x*w2.x + av.y*w2.y + av.z*w2.z + av.w*w2.w;
        }
        float2 xr = *(const float2*)&x2[r3*36 + (((cg >> 1) ^ (r3 >> 4)) << 2) + ((cg & 1) << 1)];
        float vlo = xr.x + accL;
        float vhi = xr.y + accH;
        float ps = vlo + vhi, pq = vlo*vlo + vhi*vhi;
        ps += __shfl_xor(ps, 1);  pq += __shfl_xor(pq, 1);
        ps += __shfl_xor(ps, 2);  pq += __shfl_xor(pq, 2);
        ps += __shfl_xor(ps, 4);  pq += __shfl_xor(pq, 4);
        ps += __shfl_xor(ps, 8);  pq += __shfl_xor(pq, 8);
        float mn = ps * (1.f/NC);
        float vr = pq * (1.f/NC) - mn*mn;
        float iv = rsqrtf(vr + 1e-5f);
        float2 og;
        og.x = (vlo - mn)*iv*ws_par[256 + c0]     + ws_par[288 + c0];
        og.y = (vhi - mn)*iv*ws_par[256 + c0 + 1] + ws_par[288 + c0 + 1];
        *(float2*)&xpostT[((b*NS + s)*NL + r3)*NC + c0] = og;
    }
}

// ---------------------------------------------------------------------------
// K23 v5 = R6's v4 + xpostT loads issued BEFORE the pp_w s1 loads (the
// producer-critical input leads the VMEM queue). Math identical.
// ---------------------------------------------------------------------------
__global__ __launch_bounds__(256) void k23_pair(
    const float* __restrict__ xpostT, fp pp_w,
    fp pp_b, fp ada_g, fp ada_b, fp ada_alpha,
    float* __restrict__ out)
{
    __shared__ float ppws[8*NC*NC];   // 8192 floats, 32 KB (per pass)
    __shared__ float mh[NC*66];       // raw max over tracks, [c][66]
    __shared__ float u[NCP*4*NC];     // 2048 floats
    __shared__ float nrm_s[NL];       // |m_i| per row

    const int b  = blockIdx.x >> 4;
    const int it = blockIdx.x & 15;
    const int t  = threadIdx.x;
    const int w  = t >> 6;
    const int j  = t & 63;

    // xpostT loads first (producer-critical, possibly L2-cold), then pp_w s1.
    const float4* xb4 = (const float4*)(xpostT + b*NS*NL*NC);
    float4 xv[2][4];
#pragma unroll
    for (int k = 0; k < 2; k++){
        int idx = k*256 + t;
        xv[k][0] = xb4[idx];
        xv[k][1] = xb4[512  + idx];
        xv[k][2] = xb4[1024 + idx];
        xv[k][3] = xb4[1536 + idx];
    }

    float4 s1[8];
#pragma unroll
    for (int k = 0; k < 8; k++) s1[k] = ((const float4*)pp_w)[k*256 + t];

#pragma unroll
    for (int k = 0; k < 2; k++){
        int idx = k*256 + t;
        float4 v0 = xv[k][0], v1 = xv[k][1], v2 = xv[k][2], v3 = xv[k][3];
        float m0 = fmaxf(fmaxf(v0.x, v1.x), fmaxf(v2.x, v3.x));
        float m1 = fmaxf(fmaxf(v0.y, v1.y), fmaxf(v2.y, v3.y));
        float m2 = fmaxf(fmaxf(v0.z, v1.z), fmaxf(v2.z, v3.z));
        float m3 = fmaxf(fmaxf(v0.w, v1.w), fmaxf(v2.w, v3.w));
        int l = idx >> 3, c4 = idx & 7;
        mh[(4*c4+0)*66 + l] = m0;
        mh[(4*c4+1)*66 + l] = m1;
        mh[(4*c4+2)*66 + l] = m2;
        mh[(4*c4+3)*66 + l] = m3;
    }
#pragma unroll
    for (int k = 0; k < 8; k++) ((float4*)ppws)[k*256 + t] = s1[k];
    __syncthreads();

    if (t < NL){
        float sq = 0.f;
#pragma unroll
        for (int c = 0; c < NC; c++){ float v = mh[c*66 + t]; sq += v*v; }
        nrm_s[t] = sqrtf(sq);
    }

    float4 s2[8];
#pragma unroll
    for (int k = 0; k < 8; k++) s2[k] = ((const float4*)pp_w)[2048 + k*256 + t];

    const int dq  = t & 7;            // d-quad
    const int ipz = (t >> 3) & 3;     // i within tile
    const int plz = t >> 5;           // p-slice 0..7
    const int iz  = it*4 + ipz;
    {
        float4 acc = make_float4(0.f, 0.f, 0.f, 0.f);
        const float*  mrow = &mh[iz];
        const float4* wrow = (const float4*)&ppws[plz*1024 + (dq << 2)];
#pragma unroll
        for (int c = 0; c < NC; c++){
            float  mhv = mrow[c*66];
            float4 wv  = wrow[c*8];
            acc.x += mhv*wv.x; acc.y += mhv*wv.y;
            acc.z += mhv*wv.z; acc.w += mhv*wv.w;
        }
        *(float4*)&u[plz*128 + ipz*32 + (dq << 2)] = acc;
    }
    __syncthreads();
#pragma unroll
    for (int k = 0; k < 8; k++) ((float4*)ppws)[k*256 + t] = s2[k];
    __syncthreads();

    {
        float4 acc = make_float4(0.f, 0.f, 0.f, 0.f);
        const float*  mrow = &mh[iz];
        const float4* wrow = (const float4*)&ppws[plz*1024 + (dq << 2)];
#pragma unroll
        for (int c = 0; c < NC; c++){
            float  mhv = mrow[c*66];
            float4 wv  = wrow[c*8];
            acc.x += mhv*wv.x; acc.y += mhv*wv.y;
            acc.z += mhv*wv.z; acc.w += mhv*wv.w;
        }
        *(float4*)&u[(8 + plz)*128 + ipz*32 + (dq << 2)] = acc;
    }
    __syncthreads();

    float md[NC];
#pragma unroll
    for (int c = 0; c < NC; c++) md[c] = mh[c*66 + j];

    const int i = it*4 + w;
    float f[NCP];
#pragma unroll
    for (int p = 0; p < NCP; p++){
        float a = 0.f;
#pragma unroll
        for (int k4 = 0; k4 < 8; k4++){
            float4 uv = *(const float4*)&u[p*128 + w*32 + (k4 << 2)];
            a += uv.x*md[4*k4+0] + uv.y*md[4*k4+1] + uv.z*md[4*k4+2] + uv.w*md[4*k4+3];
        }
        f[p] = a;
    }

    const float sc = 1.f / fmaxf(nrm_s[i] * nrm_s[j], 1e-6f);
    const float alpha = ada_alpha[0];
    float fsum = 0.f, fsq = 0.f;
#pragma unroll
    for (int p = 0; p < NCP; p++){
        float v = f[p]*sc + pp_b[p];
        f[p] = v; fsum += v; fsq += v*v;
    }
    float fmean = fsum * (1.f/NCP);
    float fvar  = fsq * (1.f/NCP) - fmean*fmean;
    float finv  = rsqrtf(fvar + 1e-5f);
#pragma unroll
    for (int p = 0; p < NCP; p++){
        float v = f[p] + alpha * ((f[p] - fmean)*finv*ada_g[p] + ada_b[p]);
        out[((b*NCP + p)*NL + i)*NL + j] = v / (1.f + __expf(-v));
    }
}

extern "C" void kernel_launch(void* const* d_in, const int* in_sizes, int n_in,
                              void* d_out, int out_size, void* d_ws, size_t ws_size,
                              hipStream_t stream)
{
    float* xpostT = (float*)d_ws;                    // 32*4*64*32 = 262144 f32

    k1_attn<<<NB*NS*2, 512, 0, stream>>>(
        (fp)d_in[0], (fp)d_in[1], (fp)d_in[2], (fp)d_in[3], (fp)d_in[4],
        (fp)d_in[5], (fp)d_in[6], (fp)d_in[7], (fp)d_in[8], (fp)d_in[9],
        (fp)d_in[10], (fp)d_in[11], (fp)d_in[12], (fp)d_in[13], (fp)d_in[14], (fp)d_in[15],
        (fp)d_in[16], (fp)d_in[17], (fp)d_in[18], (fp)d_in[19],
        (fp)d_in[20], (fp)d_in[21], (fp)d_in[22], (fp)d_in[23], xpostT);

    k23_pair<<<NB*16, 256, 0, stream>>>(
        xpostT, (fp)d_in[24], (fp)d_in[25], (fp)d_in[26], (fp)d_in[27], (fp)d_in[28],
        (float*)d_out);
}

// Round 9
// 135.201 us; speedup vs baseline: 1.0186x; 1.0138x over previous
//
#include <hip/hip_runtime.h>
#include <hip/hip_bf16.h>

#define NB 32
#define NS 4
#define NL 64
#define NC 32
#define NH 4
#define ND 8
#define NCP 16

using fp = const float* __restrict__;

// ---------------------------------------------------------------------------
// K1 v9 (byte-identical to R8): weight/param LDS staging, swizzled [l][36]
// tiles, pos/sig preloaded pre-barrier, 3 barriers, shfl-LN epilogue.
// ---------------------------------------------------------------------------
__global__ __launch_bounds__(512) void k1_attn(
    fp ctcf, fp hac, fp me1, fp me3, fp bulk,
    fp we_w, fp we_b, fp pos, fp mn_g, fp mn_b,
    fp wq, fp bq, fp wk, fp bk, fp wv, fp bv,
    fp wo, fp bo, fp an_g, fp an_b,
    fp conv_w, fp conv_b, fp gate_w, fp gate_b,
    float* __restrict__ xpostT)
{
    __shared__ __align__(16) float q2[NL*36];
    __shared__ __align__(16) float k2[NL*36];
    __shared__ __align__(16) float v2[NL*36];
    __shared__ __align__(16) float x2[NL*36];
    __shared__ __align__(16) float a2[NL*36];
    __shared__ float bs[32*65];
    __shared__ __align__(16) float ws_wq[NC*NC];
    __shared__ __align__(16) float ws_wk[NC*NC];
    __shared__ __align__(16) float ws_wv[NC*NC];
    __shared__ __align__(16) float ws_wo[NC*NC];
    __shared__ __align__(16) float ws_gw[NH*ND*ND];
    __shared__ __align__(16) float ws_par[352];

    const int t    = threadIdx.x;
    const int w    = t >> 6;
    const int l    = t & 63;
    const int bx   = blockIdx.x;
    const int b    = bx >> 3;
    const int s    = (bx >> 1) & 3;
    const int half = bx & 1;

    float4 pp_r[8];
#pragma unroll
    for (int k4 = 0; k4 < 8; k4++) pp_r[k4] = ((const float4*)pos)[l*8 + k4];

    fp sigp = (s == 0) ? ctcf : (s == 1) ? hac : (s == 2) ? me1 : me3;
    const float sig = sigp[b*NL + l];

    if (t < 256) ((float4*)ws_wq)[t]       = ((const float4*)wq)[t];
    else         ((float4*)ws_wk)[t - 256] = ((const float4*)wk)[t - 256];

    if (t < 256) ((float4*)ws_wv)[t] = ((const float4*)wv)[t];
    else {
        int u = t - 256;
        if (u < 64) ((float4*)ws_gw)[u] = ((const float4*)gate_w)[u];
        else if (u < 152){
            int p = u - 64;
            const float* sp = (p < 8)  ? we_w : (p < 16) ? we_b
                            : (p < 24) ? mn_g : (p < 32) ? mn_b
                            : (p < 40) ? bq   : (p < 48) ? bk
                            : (p < 56) ? bv   : (p < 64) ? bo
                            : (p < 72) ? an_g : (p < 80) ? an_b : gate_b;
            ((float4*)ws_par)[p] = ((const float4*)sp)[p & 7];
        }
    }
    if (t < 256){
        int c = t >> 3, k4 = t & 7;
        ((float4*)ws_wo)[c*8 + (k4 ^ ((c >> 1) & 7))] = ((const float4*)wo)[t];
    }
    {
        float4 v = ((const float4*)(bulk + b*NL*NL + half*32*NL))[t];
        int row = t >> 4, col = (t & 15) << 2;
        float* dst = &bs[row*65 + col];
        dst[0] = v.x; dst[1] = v.y; dst[2] = v.z; dst[3] = v.w;
    }
    __syncthreads();                            // barrier 1

    const float4* pws = (const float4*)ws_par;

    float x[NC];
    float mean = 0.f;
#pragma unroll
    for (int k4 = 0; k4 < 8; k4++){
        float4 ww = pws[k4];
        float4 wb = pws[8 + k4];
        float4 pp = pp_r[k4];
        x[4*k4+0] = sig*ww.x + wb.x + pp.x;
        x[4*k4+1] = sig*ww.y + wb.y + pp.y;
        x[4*k4+2] = sig*ww.z + wb.z + pp.z;
        x[4*k4+3] = sig*ww.w + wb.w + pp.w;
        mean += x[4*k4+0] + x[4*k4+1] + x[4*k4+2] + x[4*k4+3];
    }
    mean *= (1.f/NC);
    float var = 0.f;
#pragma unroll
    for (int c = 0; c < NC; c++){ float d = x[c] - mean; var += d*d; }
    var *= (1.f/NC);
    float inv = rsqrtf(var + 1e-5f);
#pragma unroll
    for (int k4 = 0; k4 < 8; k4++){
        float4 gg = pws[16 + k4];
        float4 bb = pws[24 + k4];
        x[4*k4+0] = (x[4*k4+0] - mean)*inv*gg.x + bb.x;
        x[4*k4+1] = (x[4*k4+1] - mean)*inv*gg.y + bb.y;
        x[4*k4+2] = (x[4*k4+2] - mean)*inv*gg.z + bb.z;
        x[4*k4+3] = (x[4*k4+3] - mean)*inv*gg.w + bb.w;
    }

    {
        float aqv[4], akv[4], avv[4];
#pragma unroll
        for (int e4 = 0; e4 < 4; e4++){
            const int e = (w << 2) + e4;
            float aq = ws_par[128 + e], ak = ws_par[160 + e], av = ws_par[192 + e];
#pragma unroll
            for (int k4 = 0; k4 < 8; k4++){
                float4 wq4 = *(const float4*)&ws_wq[e*NC + 4*k4];
                float4 wk4 = *(const float4*)&ws_wk[e*NC + 4*k4];
                float4 wv4 = *(const float4*)&ws_wv[e*NC + 4*k4];
                float x0 = x[4*k4+0], x1 = x[4*k4+1], x2v = x[4*k4+2], x3 = x[4*k4+3];
                aq += wq4.x*x0 + wq4.y*x1 + wq4.z*x2v + wq4.w*x3;
                ak += wk4.x*x0 + wk4.y*x1 + wk4.z*x2v + wk4.w*x3;
                av += wv4.x*x0 + wv4.y*x1 + wv4.z*x2v + wv4.w*x3;
            }
            aqv[e4] = aq; akv[e4] = ak; avv[e4] = av;
        }
        const int slt = ((w >> 1) ^ (l >> 4));
        const int kh  = (w & 1);
        const int off = l*36 + slt*8 + kh*4;
        *(float4*)&q2[off] = make_float4(aqv[0], aqv[1], aqv[2], aqv[3]);
        *(float4*)&k2[off] = make_float4(akv[0], akv[1], akv[2], akv[3]);
        *(float4*)&v2[off] = make_float4(avv[0], avv[1], avv[2], avv[3]);
        float xa = 0.f, xb2 = 0.f, xc = 0.f, xd = 0.f;
#pragma unroll
        for (int ww = 0; ww < 8; ww++)
            if (ww == w){ xa = x[4*ww]; xb2 = x[4*ww+1]; xc = x[4*ww+2]; xd = x[4*ww+3]; }
        *(float4*)&x2[l*36 + ((w ^ (l >> 4)) << 2)] = make_float4(xa, xb2, xc, xd);
    }
    __syncthreads();                            // barrier 2

    {
        const int h   = w >> 1;
        const int sub = ((w & 1) << 6) | l;
        const int rl  = sub >> 2;
        const int q4  = sub & 3;
        const int r   = half*32 + rl;
        const int m0  = q4 << 4;

        const int qoff = r*36 + ((h ^ (r >> 4)) << 3);
        float4 qa = *(const float4*)&q2[qoff];
        float4 qb = *(const float4*)&q2[qoff + 4];

        const float rs8 = 0.35355339059327373f;
        const float cw = conv_w[h], cb = conv_b[h];
        const float* bsr = &bs[rl*65];
        float srow[16];
        float mx = -1e30f;
#pragma unroll
        for (int mi = 0; mi < 16; mi++){
            int m  = m0 + mi;
            int kb = m*36 + ((h ^ (m >> 4)) << 3);
            float4 ka  = *(const float4*)&k2[kb];
            float4 kb4 = *(const float4*)&k2[kb + 4];
            float dot = qa.x*ka.x + qa.y*ka.y + qa.z*ka.z + qa.w*ka.w
                      + qb.x*kb4.x + qb.y*kb4.y + qb.z*kb4.z + qb.w*kb4.w;
            float vv = dot*rs8 + bsr[m]*cw + cb;
            srow[mi] = vv;
            mx = fmaxf(mx, vv);
        }
        mx = fmaxf(mx, __shfl_xor(mx, 1));
        mx = fmaxf(mx, __shfl_xor(mx, 2));
        float sm = 0.f;
#pragma unroll
        for (int mi = 0; mi < 16; mi++){ srow[mi] = __expf(srow[mi] - mx); sm += srow[mi]; }
        sm += __shfl_xor(sm, 1);
        sm += __shfl_xor(sm, 2);
        float is = 1.f / sm;

        float4 oa = make_float4(0.f,0.f,0.f,0.f);
        float4 ob = make_float4(0.f,0.f,0.f,0.f);
#pragma unroll
        for (int mi = 0; mi < 16; mi++){
            int m  = m0 + mi;
            int vb = m*36 + ((h ^ (m >> 4)) << 3);
            float a = srow[mi] * is;
            float4 va  = *(const float4*)&v2[vb];
            float4 vb4 = *(const float4*)&v2[vb + 4];
            oa.x += a*va.x;  oa.y += a*va.y;  oa.z += a*va.z;  oa.w += a*va.w;
            ob.x += a*vb4.x; ob.y += a*vb4.y; ob.z += a*vb4.z; ob.w += a*vb4.w;
        }
#define RED2(f) f += __shfl_xor(f, 1); f += __shfl_xor(f, 2);
        RED2(oa.x) RED2(oa.y) RED2(oa.z) RED2(oa.w)
        RED2(ob.x) RED2(ob.y) RED2(ob.z) RED2(ob.w)
#undef RED2

        const int c8l = q4 << 1;
        const float* gwl = &ws_gw[(h*ND + c8l)*ND];
        float4 g1 = *(const float4*)gwl;
        float4 g2 = *(const float4*)(gwl + 4);
        float4 g3 = *(const float4*)(gwl + 8);
        float4 g4 = *(const float4*)(gwl + 12);
        float gl = ws_par[320 + h*ND + c8l]
                 + g1.x*oa.x + g1.y*oa.y + g1.z*oa.z + g1.w*oa.w
                 + g2.x*ob.x + g2.y*ob.y + g2.z*ob.z + g2.w*ob.w;
        float gh = ws_par[320 + h*ND + c8l + 1]
                 + g3.x*oa.x + g3.y*oa.y + g3.z*oa.z + g3.w*oa.w
                 + g4.x*ob.x + g4.y*ob.y + g4.z*ob.z + g4.w*ob.w;
        float olo, ohi;
        if      (q4 == 0){ olo = oa.x; ohi = oa.y; }
        else if (q4 == 1){ olo = oa.z; ohi = oa.w; }
        else if (q4 == 2){ olo = ob.x; ohi = ob.y; }
        else             { olo = ob.z; ohi = ob.w; }
        float vlo = olo * (1.f/(1.f + __expf(-gl)));
        float vhi = ohi * (1.f/(1.f + __expf(-gh)));
        *(float2*)&a2[r*36 + h*8 + c8l] = make_float2(vlo, vhi);
    }
    __syncthreads();                            // barrier 3

    {
        const int rg = t >> 4;
        const int cg = t & 15;
        const int r3 = half*32 + rg;
        const int c0 = cg << 1;
        float accL = ws_par[224 + c0], accH = ws_par[224 + c0 + 1];
#pragma unroll
        for (int k4 = 0; k4 < 8; k4++){
            float4 av = *(const float4*)&a2[r3*36 + (k4 << 2)];
            float4 w1 = ((const float4*)ws_wo)[c0*8 + (k4 ^ (cg & 7))];
            float4 w2 = ((const float4*)ws_wo)[(c0 + 1)*8 + (k4 ^ (cg & 7))];
            accL += av.x*w1.x + av.y*w1.y + av.z*w1.z + av.w*w1.w;
            accH += av.x*w2.x + av.y*w2.y + av.z*w2.z + av.w*w2.w;
        }
        float2 xr = *(const float2*)&x2[r3*36 + (((cg >> 1) ^ (r3 >> 4)) << 2) + ((cg & 1) << 1)];
        float vlo = xr.x + accL;
        float vhi = xr.y + accH;
        float ps = vlo + vhi, pq = vlo*vlo + vhi*vhi;
        ps += __shfl_xor(ps, 1);  pq += __shfl_xor(pq, 1);
        ps += __shfl_xor(ps, 2);  pq += __shfl_xor(pq, 2);
        ps += __shfl_xor(ps, 4);  pq += __shfl_xor(pq, 4);
        ps += __shfl_xor(ps, 8);  pq += __shfl_xor(pq, 8);
        float mn = ps * (1.f/NC);
        float vr = pq * (1.f/NC) - mn*mn;
        float iv = rsqrtf(vr + 1e-5f);
        float2 og;
        og.x = (vlo - mn)*iv*ws_par[256 + c0]     + ws_par[288 + c0];
        og.y = (vhi - mn)*iv*ws_par[256 + c0 + 1] + ws_par[288 + c0 + 1];
        *(float2*)&xpostT[((b*NS + s)*NL + r3)*NC + c0] = og;
    }
}

// ---------------------------------------------------------------------------
// K23 v6: 256 blocks (b,itp) x 512 threads -- 2 it-tiles merged per block.
// Halves pp_w staging traffic (32->16 MB/iter) and mh redundancy (16x->8x).
// Mapping = R4 part B (validated) + R6's f4 u-pass. us stride-40 layout:
// 16B-aligned, write conflicts <=2-way (free), f-loop reads wave-uniform.
// Math identical to v5.
// ---------------------------------------------------------------------------
__global__ __launch_bounds__(512) void k23_pair(
    const float* __restrict__ xpostT, fp pp_w,
    fp pp_b, fp ada_g, fp ada_b, fp ada_alpha,
    float* __restrict__ out)
{
    __shared__ float ppws[8*NC*NC];   // 8192 floats, 32 KB (per pass)
    __shared__ float mh[NC*66];       // raw max over tracks, [c][66]
    __shared__ float us[NCP*8*40];    // [p][i_local][d] stride-40, 20 KB
    __shared__ float nrm_s[NL];

    const int b   = blockIdx.x >> 3;
    const int itp = blockIdx.x & 7;   // i rows itp*8 .. itp*8+7
    const int t   = threadIdx.x;
    const int w   = t >> 6;           // wave 0..7 (owns i_local = w)
    const int j   = t & 63;

    // xpostT loads first (producer-critical), then pp_w stage-1
    const float4* xb4 = (const float4*)(xpostT + b*NS*NL*NC);
    float4 v0 = xb4[t];
    float4 v1 = xb4[512  + t];
    float4 v2 = xb4[1024 + t];
    float4 v3 = xb4[1536 + t];

    float4 s1[4];
#pragma unroll
    for (int k = 0; k < 4; k++) s1[k] = ((const float4*)pp_w)[k*512 + t];

    {
        float m0 = fmaxf(fmaxf(v0.x, v1.x), fmaxf(v2.x, v3.x));
        float m1 = fmaxf(fmaxf(v0.y, v1.y), fmaxf(v2.y, v3.y));
        float m2 = fmaxf(fmaxf(v0.z, v1.z), fmaxf(v2.z, v3.z));
        float m3 = fmaxf(fmaxf(v0.w, v1.w), fmaxf(v2.w, v3.w));
        int l = t >> 3, c4 = t & 7;
        mh[(4*c4+0)*66 + l] = m0;
        mh[(4*c4+1)*66 + l] = m1;
        mh[(4*c4+2)*66 + l] = m2;
        mh[(4*c4+3)*66 + l] = m3;
    }
#pragma unroll
    for (int k = 0; k < 4; k++) ((float4*)ppws)[k*512 + t] = s1[k];
    __syncthreads();                            // B1: mh + ppws pass-1 ready

    if (t < NL){
        float sq = 0.f;
#pragma unroll
        for (int c = 0; c < NC; c++){ float v = mh[c*66 + t]; sq += v*v; }
        nrm_s[t] = sqrtf(sq);
    }

    // pp_w stage-2: issue now, lands during u-pass-1
    float4 s2[4];
#pragma unroll
    for (int k = 0; k < 4; k++) s2[k] = ((const float4*)pp_w)[2048 + k*512 + t];

    // u-pass decomposition: thread = (pl, ii, dq), 8x8x8 = 512
    const int dq = t & 7;
    const int ii = (t >> 3) & 7;
    const int pl = t >> 6;
    const int iz = itp*8 + ii;
    {
        float4 acc = make_float4(0.f, 0.f, 0.f, 0.f);
        const float*  mrow = &mh[iz];
        const float4* wrow = (const float4*)&ppws[pl*1024 + (dq << 2)];
#pragma unroll
        for (int c = 0; c < NC; c++){
            float  mhv = mrow[c*66];
            float4 wv  = wrow[c*8];
            acc.x += mhv*wv.x; acc.y += mhv*wv.y;
            acc.z += mhv*wv.z; acc.w += mhv*wv.w;
        }
        *(float4*)&us[pl*320 + ii*40 + (dq << 2)] = acc;
    }
    __syncthreads();                            // B2: pass-1 reads done
#pragma unroll
    for (int k = 0; k < 4; k++) ((float4*)ppws)[k*512 + t] = s2[k];
    __syncthreads();                            // B3: ppws pass-2 ready

    {
        float4 acc = make_float4(0.f, 0.f, 0.f, 0.f);
        const float*  mrow = &mh[iz];
        const float4* wrow = (const float4*)&ppws[pl*1024 + (dq << 2)];
#pragma unroll
        for (int c = 0; c < NC; c++){
            float  mhv = mrow[c*66];
            float4 wv  = wrow[c*8];
            acc.x += mhv*wv.x; acc.y += mhv*wv.y;
            acc.z += mhv*wv.z; acc.w += mhv*wv.w;
        }
        *(float4*)&us[(8 + pl)*320 + ii*40 + (dq << 2)] = acc;
    }
    __syncthreads();                            // B4: us complete

    float md[NC];
#pragma unroll
    for (int c = 0; c < NC; c++) md[c] = mh[c*66 + j];

    const int i = itp*8 + w;                    // wave w owns row i, lane = j
    float f[NCP];
#pragma unroll
    for (int p = 0; p < NCP; p++){
        float a = 0.f;
#pragma unroll
        for (int k4 = 0; k4 < 8; k4++){
            float4 uv = *(const float4*)&us[p*320 + w*40 + (k4 << 2)];
            a += uv.x*md[4*k4+0] + uv.y*md[4*k4+1] + uv.z*md[4*k4+2] + uv.w*md[4*k4+3];
        }
        f[p] = a;
    }

    const float sc = 1.f / fmaxf(nrm_s[i] * nrm_s[j], 1e-6f);
    const float alpha = ada_alpha[0];
    float fsum = 0.f, fsq = 0.f;
#pragma unroll
    for (int p = 0; p < NCP; p++){
        float v = f[p]*sc + pp_b[p];
        f[p] = v; fsum += v; fsq += v*v;
    }
    float fmean = fsum * (1.f/NCP);
    float fvar  = fsq * (1.f/NCP) - fmean*fmean;
    float finv  = rsqrtf(fvar + 1e-5f);
#pragma unroll
    for (int p = 0; p < NCP; p++){
        float v = f[p] + alpha * ((f[p] - fmean)*finv*ada_g[p] + ada_b[p]);
        out[((b*NCP + p)*NL + i)*NL + j] = v / (1.f + __expf(-v));
    }
}

extern "C" void kernel_launch(void* const* d_in, const int* in_sizes, int n_in,
                              void* d_out, int out_size, void* d_ws, size_t ws_size,
                              hipStream_t stream)
{
    float* xpostT = (float*)d_ws;                    // 32*4*64*32 = 262144 f32

    k1_attn<<<NB*NS*2, 512, 0, stream>>>(
        (fp)d_in[0], (fp)d_in[1], (fp)d_in[2], (fp)d_in[3], (fp)d_in[4],
        (fp)d_in[5], (fp)d_in[6], (fp)d_in[7], (fp)d_in[8], (fp)d_in[9],
        (fp)d_in[10], (fp)d_in[11], (fp)d_in[12], (fp)d_in[13], (fp)d_in[14], (fp)d_in[15],
        (fp)d_in[16], (fp)d_in[17], (fp)d_in[18], (fp)d_in[19],
        (fp)d_in[20], (fp)d_in[21], (fp)d_in[22], (fp)d_in[23], xpostT);

    k23_pair<<<NB*8, 512, 0, stream>>>(
        xpostT, (fp)d_in[24], (fp)d_in[25], (fp)d_in[26], (fp)d_in[27], (fp)d_in[28],
        (float*)d_out);
}

// Round 10
// 133.352 us; speedup vs baseline: 1.0327x; 1.0139x over previous
//
#include <hip/hip_runtime.h>
#include <hip/hip_bf16.h>

#define NB 32
#define NS 4
#define NL 64
#define NC 32
#define NH 4
#define ND 8
#define NCP 16

using fp = const float* __restrict__;

// ---------------------------------------------------------------------------
// K1 v10 = R9 + conv_w/conv_b staged into ws_par (kills the only mid-kernel
// global loads, which headed phase 2's chain). Math identical.
// ---------------------------------------------------------------------------
__global__ __launch_bounds__(512) void k1_attn(
    fp ctcf, fp hac, fp me1, fp me3, fp bulk,
    fp we_w, fp we_b, fp pos, fp mn_g, fp mn_b,
    fp wq, fp bq, fp wk, fp bk, fp wv, fp bv,
    fp wo, fp bo, fp an_g, fp an_b,
    fp conv_w, fp conv_b, fp gate_w, fp gate_b,
    float* __restrict__ xpostT)
{
    __shared__ __align__(16) float q2[NL*36];
    __shared__ __align__(16) float k2[NL*36];
    __shared__ __align__(16) float v2[NL*36];
    __shared__ __align__(16) float x2[NL*36];
    __shared__ __align__(16) float a2[NL*36];
    __shared__ float bs[32*65];
    __shared__ __align__(16) float ws_wq[NC*NC];
    __shared__ __align__(16) float ws_wk[NC*NC];
    __shared__ __align__(16) float ws_wv[NC*NC];
    __shared__ __align__(16) float ws_wo[NC*NC];
    __shared__ __align__(16) float ws_gw[NH*ND*ND];
    __shared__ __align__(16) float ws_par[368];
    // ws_par: we_w 0, we_b 32, mn_g 64, mn_b 96, bq 128, bk 160, bv 192,
    //         bo 224, an_g 256, an_b 288, gate_b 320, conv_w 352, conv_b 356

    const int t    = threadIdx.x;
    const int w    = t >> 6;
    const int l    = t & 63;
    const int bx   = blockIdx.x;
    const int b    = bx >> 3;
    const int s    = (bx >> 1) & 3;
    const int half = bx & 1;

    float4 pp_r[8];
#pragma unroll
    for (int k4 = 0; k4 < 8; k4++) pp_r[k4] = ((const float4*)pos)[l*8 + k4];

    fp sigp = (s == 0) ? ctcf : (s == 1) ? hac : (s == 2) ? me1 : me3;
    const float sig = sigp[b*NL + l];

    if (t < 256) ((float4*)ws_wq)[t]       = ((const float4*)wq)[t];
    else         ((float4*)ws_wk)[t - 256] = ((const float4*)wk)[t - 256];

    if (t < 256) ((float4*)ws_wv)[t] = ((const float4*)wv)[t];
    else {
        int u = t - 256;
        if (u < 64) ((float4*)ws_gw)[u] = ((const float4*)gate_w)[u];
        else if (u < 152){
            int p = u - 64;
            const float* sp = (p < 8)  ? we_w : (p < 16) ? we_b
                            : (p < 24) ? mn_g : (p < 32) ? mn_b
                            : (p < 40) ? bq   : (p < 48) ? bk
                            : (p < 56) ? bv   : (p < 64) ? bo
                            : (p < 72) ? an_g : (p < 80) ? an_b : gate_b;
            ((float4*)ws_par)[p] = ((const float4*)sp)[p & 7];
        }
        else if (u == 152) ((float4*)ws_par)[88] = *(const float4*)conv_w;
        else if (u == 153) ((float4*)ws_par)[89] = *(const float4*)conv_b;
    }
    if (t < 256){
        int c = t >> 3, k4 = t & 7;
        ((float4*)ws_wo)[c*8 + (k4 ^ ((c >> 1) & 7))] = ((const float4*)wo)[t];
    }
    {
        float4 v = ((const float4*)(bulk + b*NL*NL + half*32*NL))[t];
        int row = t >> 4, col = (t & 15) << 2;
        float* dst = &bs[row*65 + col];
        dst[0] = v.x; dst[1] = v.y; dst[2] = v.z; dst[3] = v.w;
    }
    __syncthreads();                            // barrier 1

    const float4* pws = (const float4*)ws_par;

    float x[NC];
    float mean = 0.f;
#pragma unroll
    for (int k4 = 0; k4 < 8; k4++){
        float4 ww = pws[k4];
        float4 wb = pws[8 + k4];
        float4 pp = pp_r[k4];
        x[4*k4+0] = sig*ww.x + wb.x + pp.x;
        x[4*k4+1] = sig*ww.y + wb.y + pp.y;
        x[4*k4+2] = sig*ww.z + wb.z + pp.z;
        x[4*k4+3] = sig*ww.w + wb.w + pp.w;
        mean += x[4*k4+0] + x[4*k4+1] + x[4*k4+2] + x[4*k4+3];
    }
    mean *= (1.f/NC);
    float var = 0.f;
#pragma unroll
    for (int c = 0; c < NC; c++){ float d = x[c] - mean; var += d*d; }
    var *= (1.f/NC);
    float inv = rsqrtf(var + 1e-5f);
#pragma unroll
    for (int k4 = 0; k4 < 8; k4++){
        float4 gg = pws[16 + k4];
        float4 bb = pws[24 + k4];
        x[4*k4+0] = (x[4*k4+0] - mean)*inv*gg.x + bb.x;
        x[4*k4+1] = (x[4*k4+1] - mean)*inv*gg.y + bb.y;
        x[4*k4+2] = (x[4*k4+2] - mean)*inv*gg.z + bb.z;
        x[4*k4+3] = (x[4*k4+3] - mean)*inv*gg.w + bb.w;
    }

    {
        float aqv[4], akv[4], avv[4];
#pragma unroll
        for (int e4 = 0; e4 < 4; e4++){
            const int e = (w << 2) + e4;
            float aq = ws_par[128 + e], ak = ws_par[160 + e], av = ws_par[192 + e];
#pragma unroll
            for (int k4 = 0; k4 < 8; k4++){
                float4 wq4 = *(const float4*)&ws_wq[e*NC + 4*k4];
                float4 wk4 = *(const float4*)&ws_wk[e*NC + 4*k4];
                float4 wv4 = *(const float4*)&ws_wv[e*NC + 4*k4];
                float x0 = x[4*k4+0], x1 = x[4*k4+1], x2v = x[4*k4+2], x3 = x[4*k4+3];
                aq += wq4.x*x0 + wq4.y*x1 + wq4.z*x2v + wq4.w*x3;
                ak += wk4.x*x0 + wk4.y*x1 + wk4.z*x2v + wk4.w*x3;
                av += wv4.x*x0 + wv4.y*x1 + wv4.z*x2v + wv4.w*x3;
            }
            aqv[e4] = aq; akv[e4] = ak; avv[e4] = av;
        }
        const int slt = ((w >> 1) ^ (l >> 4));
        const int kh  = (w & 1);
        const int off = l*36 + slt*8 + kh*4;
        *(float4*)&q2[off] = make_float4(aqv[0], aqv[1], aqv[2], aqv[3]);
        *(float4*)&k2[off] = make_float4(akv[0], akv[1], akv[2], akv[3]);
        *(float4*)&v2[off] = make_float4(avv[0], avv[1], avv[2], avv[3]);
        float xa = 0.f, xb2 = 0.f, xc = 0.f, xd = 0.f;
#pragma unroll
        for (int ww = 0; ww < 8; ww++)
            if (ww == w){ xa = x[4*ww]; xb2 = x[4*ww+1]; xc = x[4*ww+2]; xd = x[4*ww+3]; }
        *(float4*)&x2[l*36 + ((w ^ (l >> 4)) << 2)] = make_float4(xa, xb2, xc, xd);
    }
    __syncthreads();                            // barrier 2

    {
        const int h   = w >> 1;
        const int sub = ((w & 1) << 6) | l;
        const int rl  = sub >> 2;
        const int q4  = sub & 3;
        const int r   = half*32 + rl;
        const int m0  = q4 << 4;

        const int qoff = r*36 + ((h ^ (r >> 4)) << 3);
        float4 qa = *(const float4*)&q2[qoff];
        float4 qb = *(const float4*)&q2[qoff + 4];

        const float rs8 = 0.35355339059327373f;
        const float cw = ws_par[352 + h], cb = ws_par[356 + h];
        const float* bsr = &bs[rl*65];
        float srow[16];
        float mx = -1e30f;
#pragma unroll
        for (int mi = 0; mi < 16; mi++){
            int m  = m0 + mi;
            int kb = m*36 + ((h ^ (m >> 4)) << 3);
            float4 ka  = *(const float4*)&k2[kb];
            float4 kb4 = *(const float4*)&k2[kb + 4];
            float dot = qa.x*ka.x + qa.y*ka.y + qa.z*ka.z + qa.w*ka.w
                      + qb.x*kb4.x + qb.y*kb4.y + qb.z*kb4.z + qb.w*kb4.w;
            float vv = dot*rs8 + bsr[m]*cw + cb;
            srow[mi] = vv;
            mx = fmaxf(mx, vv);
        }
        mx = fmaxf(mx, __shfl_xor(mx, 1));
        mx = fmaxf(mx, __shfl_xor(mx, 2));
        float sm = 0.f;
#pragma unroll
        for (int mi = 0; mi < 16; mi++){ srow[mi] = __expf(srow[mi] - mx); sm += srow[mi]; }
        sm += __shfl_xor(sm, 1);
        sm += __shfl_xor(sm, 2);
        float is = 1.f / sm;

        float4 oa = make_float4(0.f,0.f,0.f,0.f);
        float4 ob = make_float4(0.f,0.f,0.f,0.f);
#pragma unroll
        for (int mi = 0; mi < 16; mi++){
            int m  = m0 + mi;
            int vb = m*36 + ((h ^ (m >> 4)) << 3);
            float a = srow[mi] * is;
            float4 va  = *(const float4*)&v2[vb];
            float4 vb4 = *(const float4*)&v2[vb + 4];
            oa.x += a*va.x;  oa.y += a*va.y;  oa.z += a*va.z;  oa.w += a*va.w;
            ob.x += a*vb4.x; ob.y += a*vb4.y; ob.z += a*vb4.z; ob.w += a*vb4.w;
        }
#define RED2(f) f += __shfl_xor(f, 1); f += __shfl_xor(f, 2);
        RED2(oa.x) RED2(oa.y) RED2(oa.z) RED2(oa.w)
        RED2(ob.x) RED2(ob.y) RED2(ob.z) RED2(ob.w)
#undef RED2

        const int c8l = q4 << 1;
        const float* gwl = &ws_gw[(h*ND + c8l)*ND];
        float4 g1 = *(const float4*)gwl;
        float4 g2 = *(const float4*)(gwl + 4);
        float4 g3 = *(const float4*)(gwl + 8);
        float4 g4 = *(const float4*)(gwl + 12);
        float gl = ws_par[320 + h*ND + c8l]
                 + g1.x*oa.x + g1.y*oa.y + g1.z*oa.z + g1.w*oa.w
                 + g2.x*ob.x + g2.y*ob.y + g2.z*ob.z + g2.w*ob.w;
        float gh = ws_par[320 + h*ND + c8l + 1]
                 + g3.x*oa.x + g3.y*oa.y + g3.z*oa.z + g3.w*oa.w
                 + g4.x*ob.x + g4.y*ob.y + g4.z*ob.z + g4.w*ob.w;
        float olo, ohi;
        if      (q4 == 0){ olo = oa.x; ohi = oa.y; }
        else if (q4 == 1){ olo = oa.z; ohi = oa.w; }
        else if (q4 == 2){ olo = ob.x; ohi = ob.y; }
        else             { olo = ob.z; ohi = ob.w; }
        float vlo = olo * (1.f/(1.f + __expf(-gl)));
        float vhi = ohi * (1.f/(1.f + __expf(-gh)));
        *(float2*)&a2[r*36 + h*8 + c8l] = make_float2(vlo, vhi);
    }
    __syncthreads();                            // barrier 3

    {
        const int rg = t >> 4;
        const int cg = t & 15;
        const int r3 = half*32 + rg;
        const int c0 = cg << 1;
        float accL = ws_par[224 + c0], accH = ws_par[224 + c0 + 1];
#pragma unroll
        for (int k4 = 0; k4 < 8; k4++){
            float4 av = *(const float4*)&a2[r3*36 + (k4 << 2)];
            float4 w1 = ((const float4*)ws_wo)[c0*8 + (k4 ^ (cg & 7))];
            float4 w2 = ((const float4*)ws_wo)[(c0 + 1)*8 + (k4 ^ (cg & 7))];
            accL += av.x*w1.x + av.y*w1.y + av.z*w1.z + av.w*w1.w;
            accH += av.x*w2.x + av.y*w2.y + av.z*w2.z + av.w*w2.w;
        }
        float2 xr = *(const float2*)&x2[r3*36 + (((cg >> 1) ^ (r3 >> 4)) << 2) + ((cg & 1) << 1)];
        float vlo = xr.x + accL;
        float vhi = xr.y + accH;
        float ps = vlo + vhi, pq = vlo*vlo + vhi*vhi;
        ps += __shfl_xor(ps, 1);  pq += __shfl_xor(pq, 1);
        ps += __shfl_xor(ps, 2);  pq += __shfl_xor(pq, 2);
        ps += __shfl_xor(ps, 4);  pq += __shfl_xor(pq, 4);
        ps += __shfl_xor(ps, 8);  pq += __shfl_xor(pq, 8);
        float mn = ps * (1.f/NC);
        float vr = pq * (1.f/NC) - mn*mn;
        float iv = rsqrtf(vr + 1e-5f);
        float2 og;
        og.x = (vlo - mn)*iv*ws_par[256 + c0]     + ws_par[288 + c0];
        og.y = (vhi - mn)*iv*ws_par[256 + c0 + 1] + ws_par[288 + c0 + 1];
        *(float2*)&xpostT[((b*NS + s)*NL + r3)*NC + c0] = og;
    }
}

// ---------------------------------------------------------------------------
// K23 v7: single-shot pp_w staging (full 64 KB in LDS; 92.7 KB total, still
// 1 block/CU). All 8 staging f4s issued at kernel start behind the xpostT
// loads; both u-halves computed back-to-back. Barriers 4 -> 2. Math
// identical to v6.
// ---------------------------------------------------------------------------
__global__ __launch_bounds__(512) void k23_pair(
    const float* __restrict__ xpostT, fp pp_w,
    fp pp_b, fp ada_g, fp ada_b, fp ada_alpha,
    float* __restrict__ out)
{
    __shared__ float ppws[16*NC*NC];  // 16384 floats, 64 KB (ALL p-slices)
    __shared__ float mh[NC*66];       // [c][66]
    __shared__ float us[NCP*8*40];    // [p][i_local][40]
    __shared__ float nrm_s[NL];

    const int b   = blockIdx.x >> 3;
    const int itp = blockIdx.x & 7;   // i rows itp*8 .. itp*8+7
    const int t   = threadIdx.x;
    const int w   = t >> 6;           // wave 0..7 (owns i_local = w)
    const int j   = t & 63;

    // xpostT loads first (producer-critical), then ALL pp_w loads
    const float4* xb4 = (const float4*)(xpostT + b*NS*NL*NC);
    float4 v0 = xb4[t];
    float4 v1 = xb4[512  + t];
    float4 v2 = xb4[1024 + t];
    float4 v3 = xb4[1536 + t];

    float4 s1[8];
#pragma unroll
    for (int k = 0; k < 8; k++) s1[k] = ((const float4*)pp_w)[k*512 + t];

    {
        float m0 = fmaxf(fmaxf(v0.x, v1.x), fmaxf(v2.x, v3.x));
        float m1 = fmaxf(fmaxf(v0.y, v1.y), fmaxf(v2.y, v3.y));
        float m2 = fmaxf(fmaxf(v0.z, v1.z), fmaxf(v2.z, v3.z));
        float m3 = fmaxf(fmaxf(v0.w, v1.w), fmaxf(v2.w, v3.w));
        int l = t >> 3, c4 = t & 7;
        mh[(4*c4+0)*66 + l] = m0;
        mh[(4*c4+1)*66 + l] = m1;
        mh[(4*c4+2)*66 + l] = m2;
        mh[(4*c4+3)*66 + l] = m3;
    }
#pragma unroll
    for (int k = 0; k < 8; k++) ((float4*)ppws)[k*512 + t] = s1[k];
    __syncthreads();                            // B1: mh + full ppws ready

    if (t < NL){
        float sq = 0.f;
#pragma unroll
        for (int c = 0; c < NC; c++){ float v = mh[c*66 + t]; sq += v*v; }
        nrm_s[t] = sqrtf(sq);
    }

    // u-passes: thread = (pl, ii, dq); both p-halves back-to-back
    const int dq = t & 7;
    const int ii = (t >> 3) & 7;
    const int pl = t >> 6;
    const int iz = itp*8 + ii;
    {
        float4 acc0 = make_float4(0.f, 0.f, 0.f, 0.f);
        float4 acc1 = make_float4(0.f, 0.f, 0.f, 0.f);
        const float*  mrow  = &mh[iz];
        const float4* wrow0 = (const float4*)&ppws[pl*1024 + (dq << 2)];
        const float4* wrow1 = (const float4*)&ppws[(8 + pl)*1024 + (dq << 2)];
#pragma unroll
        for (int c = 0; c < NC; c++){
            float  mhv = mrow[c*66];
            float4 w0  = wrow0[c*8];
            float4 w1  = wrow1[c*8];
            acc0.x += mhv*w0.x; acc0.y += mhv*w0.y;
            acc0.z += mhv*w0.z; acc0.w += mhv*w0.w;
            acc1.x += mhv*w1.x; acc1.y += mhv*w1.y;
            acc1.z += mhv*w1.z; acc1.w += mhv*w1.w;
        }
        *(float4*)&us[pl*320 + ii*40 + (dq << 2)]       = acc0;
        *(float4*)&us[(8 + pl)*320 + ii*40 + (dq << 2)] = acc1;
    }
    __syncthreads();                            // B2: us complete

    float md[NC];
#pragma unroll
    for (int c = 0; c < NC; c++) md[c] = mh[c*66 + j];

    const int i = itp*8 + w;                    // wave w owns row i, lane = j
    float f[NCP];
#pragma unroll
    for (int p = 0; p < NCP; p++){
        float a = 0.f;
#pragma unroll
        for (int k4 = 0; k4 < 8; k4++){
            float4 uv = *(const float4*)&us[p*320 + w*40 + (k4 << 2)];
            a += uv.x*md[4*k4+0] + uv.y*md[4*k4+1] + uv.z*md[4*k4+2] + uv.w*md[4*k4+3];
        }
        f[p] = a;
    }

    const float sc = 1.f / fmaxf(nrm_s[i] * nrm_s[j], 1e-6f);
    const float alpha = ada_alpha[0];
    float fsum = 0.f, fsq = 0.f;
#pragma unroll
    for (int p = 0; p < NCP; p++){
        float v = f[p]*sc + pp_b[p];
        f[p] = v; fsum += v; fsq += v*v;
    }
    float fmean = fsum * (1.f/NCP);
    float fvar  = fsq * (1.f/NCP) - fmean*fmean;
    float finv  = rsqrtf(fvar + 1e-5f);
#pragma unroll
    for (int p = 0; p < NCP; p++){
        float v = f[p] + alpha * ((f[p] - fmean)*finv*ada_g[p] + ada_b[p]);
        out[((b*NCP + p)*NL + i)*NL + j] = v / (1.f + __expf(-v));
    }
}

extern "C" void kernel_launch(void* const* d_in, const int* in_sizes, int n_in,
                              void* d_out, int out_size, void* d_ws, size_t ws_size,
                              hipStream_t stream)
{
    float* xpostT = (float*)d_ws;                    // 32*4*64*32 = 262144 f32

    k1_attn<<<NB*NS*2, 512, 0, stream>>>(
        (fp)d_in[0], (fp)d_in[1], (fp)d_in[2], (fp)d_in[3], (fp)d_in[4],
        (fp)d_in[5], (fp)d_in[6], (fp)d_in[7], (fp)d_in[8], (fp)d_in[9],
        (fp)d_in[10], (fp)d_in[11], (fp)d_in[12], (fp)d_in[13], (fp)d_in[14], (fp)d_in[15],
        (fp)d_in[16], (fp)d_in[17], (fp)d_in[18], (fp)d_in[19],
        (fp)d_in[20], (fp)d_in[21], (fp)d_in[22], (fp)d_in[23], xpostT);

    k23_pair<<<NB*8, 512, 0, stream>>>(
        xpostT, (fp)d_in[24], (fp)d_in[25], (fp)d_in[26], (fp)d_in[27], (fp)d_in[28],
        (float*)d_out);
}